// Round 6
// baseline (228.923 us; speedup 1.0000x reference)
//
#include <hip/hip_runtime.h>
#include <hip/hip_bf16.h>
#include <stdint.h>

#define BATCH 4096
#define TLEN  1024
#define NF_IT 171        // forward triple iters: steps 1..513
#define NB_IT 170        // backward triple iters: steps 1023 down to 514
#define MSTR  72         // LDS matrix row stride (elements); 144B, 16B-aligned
#define PSTR  72

typedef short bf16x8 __attribute__((ext_vector_type(8)));
typedef float f32x4  __attribute__((ext_vector_type(4)));

// ---- LDS layout (bytes). Matrices [64][MSTR] bf16 = 9216 B each ----
#define OFF_S0   0         // T0 plain (emission-folded)
#define OFF_S1   9216      // T1 plain
#define OFF_G0   18432     // T0 transposed
#define OFF_G1   27648     // T1 transposed
#define OFF_RT   18432     // triple transposed (aliases G0; G dead after phase 2)
#define OFF_RP   27648     // triple plain      (aliases G1)
#define OFF_W    36864     // 4 pair-products (transposed form), 4*9216 -> ends 73728
#define OFF_PE   73728     // float pE[2][64]
#define OFF_PIV  74240     // float piv[64]
// loop-phase region aliases W (dead after triple build):
#define OFF_PF    36864    // bf16 Pf[2][16][PSTR] = 4608
#define OFF_PB    41472    // bf16 Pb[2][16][PSTR] = 4608
#define OFF_YSF   46080    // u64 ysf[11][16] = 1408
#define OFF_YSB   47488    // u64 ysb[11][16] = 1408
#define OFF_YBALL 48896    // u64 yball[16][16] = 2048
#define OFF_PARTF 50944    // float partF[4][16] = 256
#define OFF_PARTB 51200    // float partB[4][16] = 256
#define SMEM_SZ   74496

#define MFMA(a,b,c) __builtin_amdgcn_mfma_f32_16x16x32_bf16(a,b,c,0,0,0)

// ---------------------------------------------------------------------------
// Single kernel. 256 wgs x 256 thr (4 waves); wg = one 16-batch block running
// BOTH the forward chain (steps 1..513) and backward chain (steps 1023..514)
// interleaved per iteration: each wave issues 16 fwd + 16 bwd MFMAs (two
// independent dependency chains -> ILP covers LDS latency) between a single
// barrier. Epilogue combines alpha_mid . beta_mid in-wg. One launch, no ws.
// ---------------------------------------------------------------------------
__global__ __launch_bounds__(256, 1) void hmm_fb(
    const int* __restrict__ y, const float* __restrict__ Tmat,
    const float* __restrict__ Emat, const float* __restrict__ Pi,
    float* __restrict__ out)
{
    __shared__ __align__(16) unsigned char SM[SMEM_SZ];

    const int tid  = threadIdx.x;
    const int wv   = tid >> 6;          // state tile 0..3
    const int lane = tid & 63;
    const int lr   = lane & 15;         // MFMA row/col lane (= batch col in loop)
    const int g    = lane >> 4;         // k-group
    const int R0   = blockIdx.x * 16;

    float* pE  = (float*)(SM + OFF_PE);
    float* piv = (float*)(SM + OFF_PIV);
    const f32x4 zero = {0.f, 0.f, 0.f, 0.f};

    // ---- phase 0: emission + pi softmax ----
    if (tid < 64) {
        const float e0 = Emat[tid*2+0], e1 = Emat[tid*2+1];
        const float em = fmaxf(e0, e1);
        const float p0 = __expf(e0-em), p1 = __expf(e1-em);
        const float ez = 1.0f / (p0 + p1);
        pE[tid]      = p0 * ez;
        pE[64 + tid] = p1 * ez;
        float v = Pi[tid];
        float mx = v;
        #pragma unroll
        for (int d = 1; d < 64; d <<= 1) mx = fmaxf(mx, __shfl_xor(mx, d));
        const float e = __expf(v - mx);
        float z = e;
        #pragma unroll
        for (int d = 1; d < 64; d <<= 1) z += __shfl_xor(z, d);
        piv[tid] = e / z;
    }
    __syncthreads();

    // ---- phase 1: row-softmax of T + emission fold; plain + transposed ----
    {
        const int r  = tid >> 2;          // 0..63
        const int q4 = tid & 3;           // 16 cols each
        float v[16];
        #pragma unroll
        for (int q = 0; q < 4; q++) {
            const float4 t4 = *(const float4*)(Tmat + r*64 + q4*16 + q*4);
            v[q*4+0]=t4.x; v[q*4+1]=t4.y; v[q*4+2]=t4.z; v[q*4+3]=t4.w;
        }
        float mx = v[0];
        #pragma unroll
        for (int k = 1; k < 16; k++) mx = fmaxf(mx, v[k]);
        mx = fmaxf(mx, __shfl_xor(mx, 1));
        mx = fmaxf(mx, __shfl_xor(mx, 2));
        float z = 0.f;
        #pragma unroll
        for (int k = 0; k < 16; k++) { v[k] = __expf(v[k]-mx); z += v[k]; }
        z += __shfl_xor(z, 1);
        z += __shfl_xor(z, 2);
        const float inv = 1.0f / z;
        __hip_bfloat16* S0 = (__hip_bfloat16*)(SM + OFF_S0);
        __hip_bfloat16* S1 = (__hip_bfloat16*)(SM + OFF_S1);
        __hip_bfloat16* G0 = (__hip_bfloat16*)(SM + OFF_G0);
        __hip_bfloat16* G1 = (__hip_bfloat16*)(SM + OFF_G1);
        #pragma unroll
        for (int k = 0; k < 16; k++) {
            const int j = q4*16 + k;
            const float t = v[k] * inv;
            const __hip_bfloat16 h0 = __float2bfloat16(t * pE[j]);
            const __hip_bfloat16 h1 = __float2bfloat16(t * pE[64 + j]);
            S0[r*MSTR + j] = h0;  S1[r*MSTR + j] = h1;
            G0[j*MSTR + r] = h0;  G1[j*MSTR + r] = h1;
        }
    }
    __syncthreads();

    // ---- phase 2: W_c[x][y] = (T_b2*T_b3)[y][x]; wave wv builds W_{c=wv} ----
    {
        const int c  = wv;
        const int b2 = c >> 1, b3 = c & 1;
        const __hip_bfloat16* X = (const __hip_bfloat16*)(SM + (b3 ? OFF_G1 : OFF_G0));
        const __hip_bfloat16* V = (const __hip_bfloat16*)(SM + (b2 ? OFF_S1 : OFF_S0));
        __hip_bfloat16* W = (__hip_bfloat16*)(SM + OFF_W) + c*(64*MSTR);
        #pragma unroll
        for (int xt = 0; xt < 4; xt++) {
            const bf16x8 a0 = *(const bf16x8*)(X + (xt*16+lr)*MSTR + g*8);
            const bf16x8 a1 = *(const bf16x8*)(X + (xt*16+lr)*MSTR + 32 + g*8);
            #pragma unroll
            for (int yb = 0; yb < 4; yb++) {
                const bf16x8 b0 = *(const bf16x8*)(V + (yb*16+lr)*MSTR + g*8);
                const bf16x8 b1 = *(const bf16x8*)(V + (yb*16+lr)*MSTR + 32 + g*8);
                f32x4 d = MFMA(a0, b0, zero);
                d = MFMA(a1, b1, d);
                const int ycol = yb*16 + lr, xb = xt*16 + g*4;
                W[(xb+0)*MSTR + ycol] = __float2bfloat16(d.x);
                W[(xb+1)*MSTR + ycol] = __float2bfloat16(d.y);
                W[(xb+2)*MSTR + ycol] = __float2bfloat16(d.z);
                W[(xb+3)*MSTR + ycol] = __float2bfloat16(d.w);
            }
        }
    }
    __syncthreads();

    // ---- phase 3: triples R_m = T_b1*(T_b2 T_b3), BOTH layouts; frag-load
    //      fwd set from transposed (Rt) and bwd set from plain (Rp). ----
    bf16x8 Af[8][2];      // fwd A-frags (transposed layout)
    bf16x8 Ab[8][2];      // bwd A-frags (plain layout)
    {
        __hip_bfloat16* Rt = (__hip_bfloat16*)(SM + OFF_RT);
        __hip_bfloat16* Rp = (__hip_bfloat16*)(SM + OFF_RP);
        #pragma unroll
        for (int m = 0; m < 8; m++) {
            const int b1 = m >> 2, c = m & 3;
            const __hip_bfloat16* X = (const __hip_bfloat16*)(SM + OFF_W) + c*(64*MSTR);
            const __hip_bfloat16* V = (const __hip_bfloat16*)(SM + (b1 ? OFF_S1 : OFF_S0));
            #pragma unroll
            for (int tt = 0; tt < 4; tt++) {
                const int t8 = wv*4 + tt;        // tile id 0..15
                const int xt = t8 >> 2, yb = t8 & 3;
                const bf16x8 a0 = *(const bf16x8*)(X + (xt*16+lr)*MSTR + g*8);
                const bf16x8 a1 = *(const bf16x8*)(X + (xt*16+lr)*MSTR + 32 + g*8);
                const bf16x8 b0 = *(const bf16x8*)(V + (yb*16+lr)*MSTR + g*8);
                const bf16x8 b1 = *(const bf16x8*)(V + (yb*16+lr)*MSTR + 32 + g*8);
                f32x4 d = MFMA(a0, b0, zero);
                d = MFMA(a1, b1, d);
                const int ycol = yb*16 + lr, xb = xt*16 + g*4;
                Rt[(xb+0)*MSTR + ycol] = __float2bfloat16(d.x);
                Rt[(xb+1)*MSTR + ycol] = __float2bfloat16(d.y);
                Rt[(xb+2)*MSTR + ycol] = __float2bfloat16(d.z);
                Rt[(xb+3)*MSTR + ycol] = __float2bfloat16(d.w);
                union { __hip_bfloat16 hh[4]; uint2 u; } pk;
                pk.hh[0] = __float2bfloat16(d.x);
                pk.hh[1] = __float2bfloat16(d.y);
                pk.hh[2] = __float2bfloat16(d.z);
                pk.hh[3] = __float2bfloat16(d.w);
                *(uint2*)(Rp + ycol*MSTR + xb) = pk.u;
            }
            __syncthreads();
            Af[m][0] = *(const bf16x8*)(Rt + (wv*16+lr)*MSTR + g*8);
            Af[m][1] = *(const bf16x8*)(Rt + (wv*16+lr)*MSTR + 32 + g*8);
            Ab[m][0] = *(const bf16x8*)(Rp + (wv*16+lr)*MSTR + g*8);
            Ab[m][1] = *(const bf16x8*)(Rp + (wv*16+lr)*MSTR + 32 + g*8);
            __syncthreads();
        }
    }

    // ---- phase 4: ballot-pack y -> yball; build fwd + bwd nibble streams ----
    unsigned long long* yball = (unsigned long long*)(SM + OFF_YBALL);
    #pragma unroll
    for (int q = 0; q < 4; q++) {
        const int row = wv*4 + q;
        const int* yr = y + (size_t)(R0 + row) * TLEN;
        #pragma unroll
        for (int w = 0; w < 16; w++) {
            const unsigned long long bal = __ballot(yr[w*64 + lane] != 0);
            if (lane == 0) yball[row*16 + w] = bal;
        }
    }
    __syncthreads();
    {
        unsigned long long* ysf = (unsigned long long*)(SM + OFF_YSF);
        unsigned long long* ysb = (unsigned long long*)(SM + OFF_YSB);
        const int c = tid & 15, slot = tid >> 4;
        if (slot < 11) {
            unsigned long long wf = 0ull, wb = 0ull;
            for (int n = 0; n < 16; n++) {
                const int i = slot*16 + n;
                if (i < NF_IT) {
                    const int t1 = 3*i + 1;
                    const unsigned long long bA = (yball[c*16 + (t1>>6)] >> (t1 & 63)) & 1ull;
                    const unsigned long long bB = (yball[c*16 + ((t1+1)>>6)] >> ((t1+1) & 63)) & 1ull;
                    const unsigned long long bC = (yball[c*16 + ((t1+2)>>6)] >> ((t1+2) & 63)) & 1ull;
                    wf |= ((bA<<2) | (bB<<1) | bC) << (4*n);
                }
                if (i < NB_IT) {
                    const int t = 1021 - 3*i;
                    const unsigned long long bA = (yball[c*16 + (t>>6)] >> (t & 63)) & 1ull;
                    const unsigned long long bB = (yball[c*16 + ((t+1)>>6)] >> ((t+1) & 63)) & 1ull;
                    const unsigned long long bC = (yball[c*16 + ((t+2)>>6)] >> ((t+2) & 63)) & 1ull;
                    wb |= ((bA<<2) | (bB<<1) | bC) << (4*n);
                }
            }
            ysf[slot*16 + c] = wf;
            ysb[slot*16 + c] = wb;
        }
    }

    // ---- phase 5: init Pf[0] = alpha0, Pb[0] = ones ----
    __hip_bfloat16* Pf = (__hip_bfloat16*)(SM + OFF_PF);
    __hip_bfloat16* Pb = (__hip_bfloat16*)(SM + OFF_PB);
    {
        const int b = tid >> 4, s4 = (tid & 15) * 4;
        const int y0 = (int)(yball[b*16] & 1ull);
        const float* pe = pE + y0*64;
        union { __hip_bfloat16 h[4]; uint2 u; } pk;
        pk.h[0] = __float2bfloat16(piv[s4+0]*pe[s4+0]);
        pk.h[1] = __float2bfloat16(piv[s4+1]*pe[s4+1]);
        pk.h[2] = __float2bfloat16(piv[s4+2]*pe[s4+2]);
        pk.h[3] = __float2bfloat16(piv[s4+3]*pe[s4+3]);
        *(uint2*)(Pf + b*PSTR + s4) = pk.u;
        pk.h[0] = pk.h[1] = pk.h[2] = pk.h[3] = __float2bfloat16(1.0f);
        *(uint2*)(Pb + b*PSTR + s4) = pk.u;
    }
    __syncthreads();

    // ---- phase 6: interleaved fwd+bwd main loop ----
    float laccF = 0.f, laccB = 0.f;
    unsigned long long ywf = 0ull, ywb = 0ull;
    const unsigned long long* ysf = (const unsigned long long*)(SM + OFF_YSF);
    const unsigned long long* ysb = (const unsigned long long*)(SM + OFF_YSB);
    float* partF = (float*)(SM + OFF_PARTF);
    float* partB = (float*)(SM + OFF_PARTB);

    for (int j = 0; j < NF_IT; j++) {
        const int cur = j & 1;
        const bool do_b = (j < NB_IT);
        if ((j & 15) == 0) {
            ywf = ysf[(j>>4)*16 + lr];
            ywb = ysb[(j>>4)*16 + lr];
        }
        const int idxf = (int)(ywf & 7ull);  ywf >>= 4;
        const int idxb = (int)(ywb & 7ull);  ywb >>= 4;

        const __hip_bfloat16* prf = Pf + cur*(16*PSTR) + lr*PSTR;
        const bf16x8 Bf0 = *(const bf16x8*)(prf + g*8);
        const bf16x8 Bf1 = *(const bf16x8*)(prf + 32 + g*8);
        const __hip_bfloat16* prb = Pb + cur*(16*PSTR) + lr*PSTR;
        const bf16x8 Bb0 = *(const bf16x8*)(prb + g*8);
        const bf16x8 Bb1 = *(const bf16x8*)(prb + 32 + g*8);

        // two independent 16-MFMA chains, interleaved for ILP
        f32x4 cf[8], cb[8];
        #pragma unroll
        for (int m = 0; m < 8; m++) cf[m] = MFMA(Af[m][0], Bf0, zero);
        #pragma unroll
        for (int m = 0; m < 8; m++) cb[m] = MFMA(Ab[m][0], Bb0, zero);
        #pragma unroll
        for (int m = 0; m < 8; m++) cf[m] = MFMA(Af[m][1], Bf1, cf[m]);
        #pragma unroll
        for (int m = 0; m < 8; m++) cb[m] = MFMA(Ab[m][1], Bb1, cb[m]);

        // fwd select
        {
            const bool s1 = idxf & 1, s2 = idxf & 2, s3 = idxf & 4;
            const f32x4 t0 = s1 ? cf[1] : cf[0];
            const f32x4 t1 = s1 ? cf[3] : cf[2];
            const f32x4 t2 = s1 ? cf[5] : cf[4];
            const f32x4 t3 = s1 ? cf[7] : cf[6];
            const f32x4 u0 = s2 ? t1 : t0;
            const f32x4 u1 = s2 ? t3 : t2;
            f32x4 Dn = s3 ? u1 : u0;

            if ((j & 3) == 0 && j > 0) {
                const float Sp = partF[lr] + partF[16+lr] + partF[32+lr] + partF[48+lr];
                laccF += __logf(Sp);
                Dn *= __builtin_amdgcn_rcpf(Sp);
            }
            if ((j & 3) == 3) {
                float p = Dn.x + Dn.y + Dn.z + Dn.w;
                p += __shfl_xor(p, 16);
                p += __shfl_xor(p, 32);
                if (lane < 16) partF[wv*16 + lane] = p;
            }
            union { __hip_bfloat16 h[4]; uint2 u; } pk;
            pk.h[0] = __float2bfloat16(Dn.x);
            pk.h[1] = __float2bfloat16(Dn.y);
            pk.h[2] = __float2bfloat16(Dn.z);
            pk.h[3] = __float2bfloat16(Dn.w);
            *(uint2*)(Pf + (cur^1)*(16*PSTR) + lr*PSTR + wv*16 + g*4) = pk.u;
        }
        // bwd select
        if (do_b) {
            const bool s1 = idxb & 1, s2 = idxb & 2, s3 = idxb & 4;
            const f32x4 t0 = s1 ? cb[1] : cb[0];
            const f32x4 t1 = s1 ? cb[3] : cb[2];
            const f32x4 t2 = s1 ? cb[5] : cb[4];
            const f32x4 t3 = s1 ? cb[7] : cb[6];
            const f32x4 u0 = s2 ? t1 : t0;
            const f32x4 u1 = s2 ? t3 : t2;
            f32x4 Dn = s3 ? u1 : u0;

            if ((j & 3) == 0 && j > 0) {
                const float Sp = partB[lr] + partB[16+lr] + partB[32+lr] + partB[48+lr];
                laccB += __logf(Sp);
                Dn *= __builtin_amdgcn_rcpf(Sp);
            }
            if ((j & 3) == 3) {
                float p = Dn.x + Dn.y + Dn.z + Dn.w;
                p += __shfl_xor(p, 16);
                p += __shfl_xor(p, 32);
                if (lane < 16) partB[wv*16 + lane] = p;
            }
            union { __hip_bfloat16 h[4]; uint2 u; } pk;
            pk.h[0] = __float2bfloat16(Dn.x);
            pk.h[1] = __float2bfloat16(Dn.y);
            pk.h[2] = __float2bfloat16(Dn.z);
            pk.h[3] = __float2bfloat16(Dn.w);
            *(uint2*)(Pb + (cur^1)*(16*PSTR) + lr*PSTR + wv*16 + g*4) = pk.u;
        }
        __syncthreads();
    }

    // ---- epilogue (in-wg): logprob[b] = laccF + laccB + log(Pf_fin . Pb_fin)
    //      fwd final in buf 1 (last write j=170), bwd final in buf 0 (j=169).
    if (wv == 0) {
        const __hip_bfloat16* pf = Pf + 1*(16*PSTR) + lr*PSTR;
        const __hip_bfloat16* pb = Pb + 0*(16*PSTR) + lr*PSTR;
        float dot = 0.f;
        #pragma unroll
        for (int k = 0; k < 16; k++) {
            const int s = g*16 + k;
            dot += __bfloat162float(pf[s]) * __bfloat162float(pb[s]);
        }
        dot += __shfl_xor(dot, 16);
        dot += __shfl_xor(dot, 32);
        float lp = laccF + laccB + __logf(dot);
        lp += __shfl_xor(lp, 1);
        lp += __shfl_xor(lp, 2);
        lp += __shfl_xor(lp, 4);
        lp += __shfl_xor(lp, 8);
        if (lane == 0) atomicAdd(out, lp * (1.0f / BATCH));
    }
}

// ---------------------------------------------------------------------------
extern "C" void kernel_launch(void* const* d_in, const int* in_sizes, int n_in,
                              void* d_out, int out_size, void* d_ws, size_t ws_size,
                              hipStream_t stream) {
    const int*   y  = (const int*)  d_in[0];
    const float* T  = (const float*)d_in[1];
    const float* E  = (const float*)d_in[2];
    const float* Pi = (const float*)d_in[3];
    float* out = (float*)d_out;
    (void)d_ws; (void)ws_size;

    hipMemsetAsync(out, 0, sizeof(float), stream);
    hipLaunchKernelGGL(hmm_fb, dim3(BATCH/16), dim3(256), 0, stream, y, T, E, Pi, out);
}

// Round 8
// 185.343 us; speedup vs baseline: 1.2351x; 1.2351x over previous
//
#include <hip/hip_runtime.h>
#include <hip/hip_bf16.h>
#include <stdint.h>

#define BATCH 4096
#define TLEN  1024
#define NF_IT 128        // fwd: 4-step iters, y_1..y_512
#define NB_IT 127        // bwd: 4-step iters, y_516..y_1023 (+1 k3 iter for y_513..515)
#define MSTR  72         // pre-kernel LDS matrix row stride (elements)
#define PSTR  72         // main-kernel alpha row stride (elements)

typedef short bf16x8 __attribute__((ext_vector_type(8)));
typedef float f32x4  __attribute__((ext_vector_type(4)));

#define MFMA(a,b,c) __builtin_amdgcn_mfma_f32_16x16x32_bf16(a,b,c,0,0,0)

// ---- ws layout (bytes) ----  (C3P is 4*64*64*2 = 32768 B — R7 bug was here)
#define WS_C4T 0          // bf16 C4t[8][64][64]: C4t[m][y][x] = C_m[x][y] (fwd A, transposed)
#define WS_C4P 65536      // bf16 C4p[8][64][64]: plain (bwd A)
#define WS_C3P 131072     // bf16 C3p[4][64][64]: plain (bwd k3 remainder) -> ends 163840
#define WS_PE  163840     // float pE[2][64]
#define WS_PIV 164352     // float piv[64]
#define WS_AM  164608     // bf16 alpha_mid[4096][64] -> ends 688896
#define WS_BM  688896     // bf16 beta_mid [4096][64] -> ends 1213184
#define WS_LF  1213184    // f32 laccF[4096]
#define WS_LB  1229568    // f32 laccB[4096] -> ends 1245952

// ---- pre-kernel LDS (bytes) ----
#define PT_T   0
#define PT_VP0 9216
#define PT_VPD 18432
#define PT_VT0 27648
#define PT_VTD 36864
#define PT_WP0 46080
#define PT_WPD 55296
#define PT_PT  64512
#define PT_PE  73728
#define PT_PIV 74240
#define PRE_SZ 74496

// ---------------------------------------------------------------------------
// Pre-kernel (1 wg x 256): builds the multilinear 4-step bases
//   C_S = T Dh(b1) T Dh(b2) T Dh(b3) T,  Dh(0)=D0=diag(e0), Dh(1)=Delta=diag(e1-e0)
// via V_x = Dh(x)*T (diag fold), W_x = T*V_x, P_c = V_a*V_b, C = W*P (MFMA),
// plus the k3 bases C3 = W*V. Stores fwd-transposed + bwd-plain to ws.
// ---------------------------------------------------------------------------
__global__ __launch_bounds__(256) void hmm_pre(
    const float* __restrict__ Tmat, const float* __restrict__ Emat,
    const float* __restrict__ Pi, unsigned char* __restrict__ ws,
    float* __restrict__ out)
{
    __shared__ __align__(16) unsigned char SM[PRE_SZ];
    const int tid = threadIdx.x;
    const int wv  = tid >> 6;
    const int lane = tid & 63;
    const int lr  = lane & 15;
    const int g   = lane >> 4;
    float* pE  = (float*)(SM + PT_PE);
    float* piv = (float*)(SM + PT_PIV);
    const f32x4 zero = {0.f, 0.f, 0.f, 0.f};

    // phase 0: emission + pi softmax; export pE/piv; zero out
    if (tid < 64) {
        const float e0 = Emat[tid*2+0], e1 = Emat[tid*2+1];
        const float em = fmaxf(e0, e1);
        const float p0 = __expf(e0-em), p1 = __expf(e1-em);
        const float ez = 1.0f / (p0 + p1);
        pE[tid]      = p0 * ez;
        pE[64 + tid] = p1 * ez;
        ((float*)(ws + WS_PE))[tid]      = p0 * ez;
        ((float*)(ws + WS_PE))[64 + tid] = p1 * ez;
        float v = Pi[tid];
        float mx = v;
        #pragma unroll
        for (int d = 1; d < 64; d <<= 1) mx = fmaxf(mx, __shfl_xor(mx, d));
        const float e = __expf(v - mx);
        float z = e;
        #pragma unroll
        for (int d = 1; d < 64; d <<= 1) z += __shfl_xor(z, d);
        piv[tid] = e / z;
        ((float*)(ws + WS_PIV))[tid] = e / z;
        if (tid == 0) *out = 0.f;
    }
    __syncthreads();

    // phase 1: row-softmax of T; build T plain, V0/VD plain + transposed
    {
        const int r  = tid >> 2;
        const int q4 = tid & 3;
        float v[16];
        #pragma unroll
        for (int q = 0; q < 4; q++) {
            const float4 t4 = *(const float4*)(Tmat + r*64 + q4*16 + q*4);
            v[q*4+0]=t4.x; v[q*4+1]=t4.y; v[q*4+2]=t4.z; v[q*4+3]=t4.w;
        }
        float mx = v[0];
        #pragma unroll
        for (int k = 1; k < 16; k++) mx = fmaxf(mx, v[k]);
        mx = fmaxf(mx, __shfl_xor(mx, 1));
        mx = fmaxf(mx, __shfl_xor(mx, 2));
        float z = 0.f;
        #pragma unroll
        for (int k = 0; k < 16; k++) { v[k] = __expf(v[k]-mx); z += v[k]; }
        z += __shfl_xor(z, 1);
        z += __shfl_xor(z, 2);
        const float inv = 1.0f / z;
        const float e0r = pE[r], dr = pE[64+r] - pE[r];
        __hip_bfloat16* Tp  = (__hip_bfloat16*)(SM + PT_T);
        __hip_bfloat16* Vp0 = (__hip_bfloat16*)(SM + PT_VP0);
        __hip_bfloat16* VpD = (__hip_bfloat16*)(SM + PT_VPD);
        __hip_bfloat16* Vt0 = (__hip_bfloat16*)(SM + PT_VT0);
        __hip_bfloat16* VtD = (__hip_bfloat16*)(SM + PT_VTD);
        #pragma unroll
        for (int k = 0; k < 16; k++) {
            const int j = q4*16 + k;
            const float t = v[k] * inv;
            Tp [r*MSTR + j] = __float2bfloat16(t);
            const __hip_bfloat16 h0 = __float2bfloat16(e0r * t);
            const __hip_bfloat16 hd = __float2bfloat16(dr  * t);
            Vp0[r*MSTR + j] = h0;  VpD[r*MSTR + j] = hd;
            Vt0[j*MSTR + r] = h0;  VtD[j*MSTR + r] = hd;
        }
    }
    __syncthreads();

    // phase 2: W_x = T * V_x  (x in {0,D}), store plain
    #pragma unroll
    for (int xw = 0; xw < 2; xw++) {
        const __hip_bfloat16* A = (const __hip_bfloat16*)(SM + PT_T);
        const __hip_bfloat16* B = (const __hip_bfloat16*)(SM + (xw ? PT_VTD : PT_VT0));
        __hip_bfloat16* W = (__hip_bfloat16*)(SM + (xw ? PT_WPD : PT_WP0));
        #pragma unroll
        for (int tt = 0; tt < 4; tt++) {
            const int t8 = wv*4 + tt, xt = t8 >> 2, yb = t8 & 3;
            const bf16x8 a0 = *(const bf16x8*)(A + (xt*16+lr)*MSTR + g*8);
            const bf16x8 a1 = *(const bf16x8*)(A + (xt*16+lr)*MSTR + 32 + g*8);
            const bf16x8 b0 = *(const bf16x8*)(B + (yb*16+lr)*MSTR + g*8);
            const bf16x8 b1 = *(const bf16x8*)(B + (yb*16+lr)*MSTR + 32 + g*8);
            f32x4 d = MFMA(a0, b0, zero);
            d = MFMA(a1, b1, d);
            const int ycol = yb*16 + lr, xb = xt*16 + g*4;
            W[(xb+0)*MSTR + ycol] = __float2bfloat16(d.x);
            W[(xb+1)*MSTR + ycol] = __float2bfloat16(d.y);
            W[(xb+2)*MSTR + ycol] = __float2bfloat16(d.z);
            W[(xb+3)*MSTR + ycol] = __float2bfloat16(d.w);
        }
    }
    __syncthreads();

    // phase 3: for c=(b2,b3): Pt = (V_b2 * V_b3)^T, then C_{b1,c} = W_b1 * P -> ws
    __hip_bfloat16* gC4p = (__hip_bfloat16*)(ws + WS_C4P);
    __hip_bfloat16* gC4t = (__hip_bfloat16*)(ws + WS_C4T);
    for (int c = 0; c < 4; c++) {
        const int b2 = c >> 1, b3 = c & 1;
        {
            const __hip_bfloat16* A = (const __hip_bfloat16*)(SM + (b2 ? PT_VPD : PT_VP0));
            const __hip_bfloat16* B = (const __hip_bfloat16*)(SM + (b3 ? PT_VTD : PT_VT0));
            __hip_bfloat16* Pt = (__hip_bfloat16*)(SM + PT_PT);
            #pragma unroll
            for (int tt = 0; tt < 4; tt++) {
                const int t8 = wv*4 + tt, xt = t8 >> 2, yb = t8 & 3;
                const bf16x8 a0 = *(const bf16x8*)(A + (xt*16+lr)*MSTR + g*8);
                const bf16x8 a1 = *(const bf16x8*)(A + (xt*16+lr)*MSTR + 32 + g*8);
                const bf16x8 b0 = *(const bf16x8*)(B + (yb*16+lr)*MSTR + g*8);
                const bf16x8 b1 = *(const bf16x8*)(B + (yb*16+lr)*MSTR + 32 + g*8);
                f32x4 d = MFMA(a0, b0, zero);
                d = MFMA(a1, b1, d);
                const int ycol = yb*16 + lr, xb = xt*16 + g*4;
                union { __hip_bfloat16 hh[4]; uint2 u; } pk;
                pk.hh[0] = __float2bfloat16(d.x);
                pk.hh[1] = __float2bfloat16(d.y);
                pk.hh[2] = __float2bfloat16(d.z);
                pk.hh[3] = __float2bfloat16(d.w);
                *(uint2*)(Pt + ycol*MSTR + xb) = pk.u;
            }
        }
        __syncthreads();
        for (int sa = 0; sa < 2; sa++) {
            const int m = (sa << 2) | c;     // bit2=slot1(a), bit1=slot2(b), bit0=slot3(c)
            const __hip_bfloat16* A = (const __hip_bfloat16*)(SM + (sa ? PT_WPD : PT_WP0));
            const __hip_bfloat16* B = (const __hip_bfloat16*)(SM + PT_PT);
            #pragma unroll
            for (int tt = 0; tt < 4; tt++) {
                const int t8 = wv*4 + tt, xt = t8 >> 2, yb = t8 & 3;
                const bf16x8 a0 = *(const bf16x8*)(A + (xt*16+lr)*MSTR + g*8);
                const bf16x8 a1 = *(const bf16x8*)(A + (xt*16+lr)*MSTR + 32 + g*8);
                const bf16x8 b0 = *(const bf16x8*)(B + (yb*16+lr)*MSTR + g*8);
                const bf16x8 b1 = *(const bf16x8*)(B + (yb*16+lr)*MSTR + 32 + g*8);
                f32x4 d = MFMA(a0, b0, zero);
                d = MFMA(a1, b1, d);
                const int ycol = yb*16 + lr, xb = xt*16 + g*4;
                gC4p[m*4096 + (xb+0)*64 + ycol] = __float2bfloat16(d.x);
                gC4p[m*4096 + (xb+1)*64 + ycol] = __float2bfloat16(d.y);
                gC4p[m*4096 + (xb+2)*64 + ycol] = __float2bfloat16(d.z);
                gC4p[m*4096 + (xb+3)*64 + ycol] = __float2bfloat16(d.w);
                union { __hip_bfloat16 hh[4]; uint2 u; } pk;
                pk.hh[0] = __float2bfloat16(d.x);
                pk.hh[1] = __float2bfloat16(d.y);
                pk.hh[2] = __float2bfloat16(d.z);
                pk.hh[3] = __float2bfloat16(d.w);
                *(uint2*)(gC4t + m*4096 + ycol*64 + xb) = pk.u;
            }
        }
        __syncthreads();   // before Pt reuse
    }

    // phase 4: k3 bases C3_{sa,sb} = W_sa * V_sb -> ws plain (bit1=slot1(a), bit0=slot2(b))
    __hip_bfloat16* gC3 = (__hip_bfloat16*)(ws + WS_C3P);
    for (int mm = 0; mm < 4; mm++) {
        const int sa = mm >> 1, sb = mm & 1;
        const __hip_bfloat16* A = (const __hip_bfloat16*)(SM + (sa ? PT_WPD : PT_WP0));
        const __hip_bfloat16* B = (const __hip_bfloat16*)(SM + (sb ? PT_VTD : PT_VT0));
        #pragma unroll
        for (int tt = 0; tt < 4; tt++) {
            const int t8 = wv*4 + tt, xt = t8 >> 2, yb = t8 & 3;
            const bf16x8 a0 = *(const bf16x8*)(A + (xt*16+lr)*MSTR + g*8);
            const bf16x8 a1 = *(const bf16x8*)(A + (xt*16+lr)*MSTR + 32 + g*8);
            const bf16x8 b0 = *(const bf16x8*)(B + (yb*16+lr)*MSTR + g*8);
            const bf16x8 b1 = *(const bf16x8*)(B + (yb*16+lr)*MSTR + 32 + g*8);
            f32x4 d = MFMA(a0, b0, zero);
            d = MFMA(a1, b1, d);
            const int ycol = yb*16 + lr, xb = xt*16 + g*4;
            gC3[mm*4096 + (xb+0)*64 + ycol] = __float2bfloat16(d.x);
            gC3[mm*4096 + (xb+1)*64 + ycol] = __float2bfloat16(d.y);
            gC3[mm*4096 + (xb+2)*64 + ycol] = __float2bfloat16(d.z);
            gC3[mm*4096 + (xb+3)*64 + ycol] = __float2bfloat16(d.w);
        }
    }
}

// ---- main-kernel LDS (bytes) ----
#define MK_P    0        // bf16 P[2][16][PSTR] = 4608
#define MK_YS   4608     // u64 ys[8][16]
#define MK_YB   5632     // u64 yball[16][16]
#define MK_PART 7680     // f32 part[2][4][16]
#define MAIN_SZ 8192

// ---------------------------------------------------------------------------
// Main: 512 wgs x 256 thr. wg = (16-batch block, dir). 4-step iteration:
// 16 MFMAs against the 8 bases, 28-fmac multilinear combine (weights = y-bit
// products), emission tail (fwd: post-multiply; bwd: pre-applied at write),
// deferred renorm every iter. Same P/barrier skeleton as R5.
// ---------------------------------------------------------------------------
__global__ __launch_bounds__(256, 2) void hmm_main(
    const int* __restrict__ y, const unsigned char* __restrict__ ws,
    unsigned char* __restrict__ wso)
{
    __shared__ __align__(16) unsigned char SM[MAIN_SZ];
    const int tid  = threadIdx.x;
    const int wv   = tid >> 6;
    const int lane = tid & 63;
    const int lr   = lane & 15;
    const int g    = lane >> 4;
    const int dir  = blockIdx.x & 1;
    const int R0   = (blockIdx.x >> 1) * 16;
    const bool is_fwd = (dir == 0);
    const f32x4 zero = {0.f, 0.f, 0.f, 0.f};

    // A-frags: 8 bases x 2 K-halves (fwd: transposed set, bwd: plain set)
    bf16x8 Afr[8][2];
    {
        const __hip_bfloat16* Ab = (const __hip_bfloat16*)(ws + (is_fwd ? WS_C4T : WS_C4P));
        const int row = wv*16 + lr;
        #pragma unroll
        for (int m = 0; m < 8; m++) {
            Afr[m][0] = *(const bf16x8*)(Ab + m*4096 + row*64 + g*8);
            Afr[m][1] = *(const bf16x8*)(Ab + m*4096 + row*64 + 32 + g*8);
        }
    }
    // emission vectors for this lane's 4 output states
    const float* pE = (const float*)(ws + WS_PE);
    const int s0 = wv*16 + g*4;
    const f32x4 E0v = *(const f32x4*)(pE + s0);
    const f32x4 E1v = *(const f32x4*)(pE + 64 + s0);

    // ballot-pack y
    unsigned long long* yball = (unsigned long long*)(SM + MK_YB);
    #pragma unroll
    for (int q = 0; q < 4; q++) {
        const int row = wv*4 + q;
        const int* yr = y + (size_t)(R0 + row) * TLEN;
        #pragma unroll
        for (int w = 0; w < 16; w++) {
            const unsigned long long bal = __ballot(yr[w*64 + lane] != 0);
            if (lane == 0) yball[row*16 + w] = bal;
        }
    }
    __syncthreads();

    // nibble streams: fwd nib_j = y[4j+1..4j+4]; bwd nib_j = y[s..s+3], s=1020-4j;
    // bwd nib_127 = y513 | y514<<1 | y515<<2 | y515<<3
    {
        unsigned long long* ys = (unsigned long long*)(SM + MK_YS);
        const int c = tid & 15, slot = tid >> 4;
        if (slot < 8) {
            unsigned long long wd = 0ull;
            for (int n = 0; n < 16; n++) {
                const int j = slot*16 + n;
                unsigned long long nib;
                if (is_fwd) {
                    const int t1 = 4*j + 1;
                    const unsigned long long bA = (yball[c*16 + ((t1  )>>6)] >> ((t1  ) & 63)) & 1ull;
                    const unsigned long long bB = (yball[c*16 + ((t1+1)>>6)] >> ((t1+1) & 63)) & 1ull;
                    const unsigned long long bC = (yball[c*16 + ((t1+2)>>6)] >> ((t1+2) & 63)) & 1ull;
                    const unsigned long long bD = (yball[c*16 + ((t1+3)>>6)] >> ((t1+3) & 63)) & 1ull;
                    nib = bA | (bB<<1) | (bC<<2) | (bD<<3);
                } else if (j < 127) {
                    const int s = 1020 - 4*j;
                    const unsigned long long bA = (yball[c*16 + ((s  )>>6)] >> ((s  ) & 63)) & 1ull;
                    const unsigned long long bB = (yball[c*16 + ((s+1)>>6)] >> ((s+1) & 63)) & 1ull;
                    const unsigned long long bC = (yball[c*16 + ((s+2)>>6)] >> ((s+2) & 63)) & 1ull;
                    const unsigned long long bD = (yball[c*16 + ((s+3)>>6)] >> ((s+3) & 63)) & 1ull;
                    nib = bA | (bB<<1) | (bC<<2) | (bD<<3);
                } else {
                    const unsigned long long bA = (yball[c*16 + (513>>6)] >> (513 & 63)) & 1ull;
                    const unsigned long long bB = (yball[c*16 + (514>>6)] >> (514 & 63)) & 1ull;
                    const unsigned long long bC = (yball[c*16 + (515>>6)] >> (515 & 63)) & 1ull;
                    nib = bA | (bB<<1) | (bC<<2) | (bC<<3);
                }
                wd |= nib << (4*n);
            }
            ys[slot*16 + c] = wd;
        }
    }

    // init P[0]: fwd alpha0 = piv*e^{(y0)}; bwd ones*e^{(y1023)}
    __hip_bfloat16* P = (__hip_bfloat16*)(SM + MK_P);
    {
        const int b = tid >> 4, s4 = (tid & 15) * 4;
        union { __hip_bfloat16 h[4]; uint2 u; } pk;
        if (is_fwd) {
            const int y0 = (int)(yball[b*16] & 1ull);
            const float4 pe = *(const float4*)(pE + y0*64 + s4);
            const float4 pv = *(const float4*)((const float*)(ws + WS_PIV) + s4);
            pk.h[0] = __float2bfloat16(pv.x * pe.x);
            pk.h[1] = __float2bfloat16(pv.y * pe.y);
            pk.h[2] = __float2bfloat16(pv.z * pe.z);
            pk.h[3] = __float2bfloat16(pv.w * pe.w);
        } else {
            const int yl = (int)((yball[b*16 + 15] >> 63) & 1ull);
            const float4 pe = *(const float4*)(pE + yl*64 + s4);
            pk.h[0] = __float2bfloat16(pe.x);
            pk.h[1] = __float2bfloat16(pe.y);
            pk.h[2] = __float2bfloat16(pe.z);
            pk.h[3] = __float2bfloat16(pe.w);
        }
        *(uint2*)(P + b*PSTR + s4) = pk.u;
    }
    __syncthreads();

    // main loop
    float lacc = 0.f;
    unsigned long long yw = 0ull, ywn = 0ull;
    const unsigned long long* ys = (const unsigned long long*)(SM + MK_YS);
    float* part = (float*)(SM + MK_PART);
    const int nit = is_fwd ? NF_IT : NB_IT;

    for (int j = 0; j < nit; j++) {
        const int cur = j & 1;
        if ((j & 15) == 0) {
            const int w = j >> 4;
            yw  = ys[w*16 + lr];
            ywn = ys[((w < 7) ? w+1 : 7)*16 + lr];
        }
        const int nib = (int)(yw & 15ull);
        // bwd write-scale bit = bit3 of NEXT nibble
        const int tb = is_fwd ? ((nib >> 3) & 1)
                              : (int)((((j & 15) == 15) ? (ywn >> 3) : (yw >> 7)) & 1ull);
        yw >>= 4;

        const __hip_bfloat16* prow = P + cur*(16*PSTR) + lr*PSTR;
        const bf16x8 B0 = *(const bf16x8*)(prow + g*8);
        const bf16x8 B1 = *(const bf16x8*)(prow + 32 + g*8);

        f32x4 d[8];
        #pragma unroll
        for (int m = 0; m < 8; m++) d[m] = MFMA(Afr[m][0], B0, zero);
        #pragma unroll
        for (int m = 0; m < 8; m++) d[m] = MFMA(Afr[m][1], B1, d[m]);

        // multilinear combine: w[m] = a^bit2 * b^bit1 * c^bit0
        const float fa = (nib & 1) ? 1.0f : 0.0f;   // slot1 -> bit2 of m
        const float fb = (nib & 2) ? 1.0f : 0.0f;   // slot2 -> bit1
        const float fc = (nib & 4) ? 1.0f : 0.0f;   // slot3 -> bit0
        const float fab = fa*fb, fac = fa*fc, fbc = fb*fc, fabc = fab*fc;
        f32x4 Dn = d[0];
        Dn += fc   * d[1];
        Dn += fb   * d[2];
        Dn += fbc  * d[3];
        Dn += fa   * d[4];
        Dn += fac  * d[5];
        Dn += fab  * d[6];
        Dn += fabc * d[7];

        // deferred renorm + emission tail
        float rs = 1.0f;
        if (j > 0) {
            const float* pc = part + cur*64;
            const float Sp = pc[lr] + pc[16+lr] + pc[32+lr] + pc[48+lr];
            lacc += __logf(Sp);
            rs = __builtin_amdgcn_rcpf(Sp);
        }
        const f32x4 ev = tb ? E1v : E0v;
        f32x4 val = Dn * ev;
        val *= rs;

        // column sums for next iter (double-buffered)
        float p = val.x + val.y + val.z + val.w;
        p += __shfl_xor(p, 16);
        p += __shfl_xor(p, 32);
        if (lane < 16) part[(cur^1)*64 + wv*16 + lane] = p;

        union { __hip_bfloat16 h[4]; uint2 u; } pk;
        pk.h[0] = __float2bfloat16(val.x);
        pk.h[1] = __float2bfloat16(val.y);
        pk.h[2] = __float2bfloat16(val.z);
        pk.h[3] = __float2bfloat16(val.w);
        *(uint2*)(P + (cur^1)*(16*PSTR) + lr*PSTR + wv*16 + g*4) = pk.u;
        __syncthreads();
    }

    if (is_fwd) {
        // final alpha_512 in P[0]; copy to ws + laccF
        const int b = tid >> 4, s4 = (tid & 15) * 4;
        __hip_bfloat16* am = (__hip_bfloat16*)(wso + WS_AM);
        *(uint2*)(am + (size_t)(R0 + b)*64 + s4) = *(const uint2*)(P + b*PSTR + s4);
        if (wv == 0 && lane < 16)
            ((float*)(wso + WS_LF))[R0 + lane] = lacc;
    } else {
        // k3 remainder: beta_512 = M3(y513,y514) * (beta in P[1]) then renorm
        bf16x8 Cfr[4][2];
        {
            const __hip_bfloat16* Cb = (const __hip_bfloat16*)(ws + WS_C3P);
            const int row = wv*16 + lr;
            #pragma unroll
            for (int mm = 0; mm < 4; mm++) {
                Cfr[mm][0] = *(const bf16x8*)(Cb + mm*4096 + row*64 + g*8);
                Cfr[mm][1] = *(const bf16x8*)(Cb + mm*4096 + row*64 + 32 + g*8);
            }
        }
        const int nib = (int)(yw & 15ull);      // bit0=y513(a), bit1=y514(b)
        const __hip_bfloat16* prow = P + 1*(16*PSTR) + lr*PSTR;
        const bf16x8 B0 = *(const bf16x8*)(prow + g*8);
        const bf16x8 B1 = *(const bf16x8*)(prow + 32 + g*8);
        f32x4 d3[4];
        #pragma unroll
        for (int mm = 0; mm < 4; mm++) d3[mm] = MFMA(Cfr[mm][0], B0, zero);
        #pragma unroll
        for (int mm = 0; mm < 4; mm++) d3[mm] = MFMA(Cfr[mm][1], B1, d3[mm]);
        const float fa = (nib & 1) ? 1.0f : 0.0f;   // a -> bit1 of mm
        const float fb = (nib & 2) ? 1.0f : 0.0f;   // b -> bit0
        f32x4 Dn = d3[0];
        Dn += fb * d3[1];
        Dn += fa * d3[2];
        Dn += (fa*fb) * d3[3];
        const float* pc = part + 1*64;              // written at j=126
        const float Sp = pc[lr] + pc[16+lr] + pc[32+lr] + pc[48+lr];
        lacc += __logf(Sp);
        Dn *= __builtin_amdgcn_rcpf(Sp);
        __hip_bfloat16* bm = (__hip_bfloat16*)(wso + WS_BM);
        union { __hip_bfloat16 h[4]; uint2 u; } pk;
        pk.h[0] = __float2bfloat16(Dn.x);
        pk.h[1] = __float2bfloat16(Dn.y);
        pk.h[2] = __float2bfloat16(Dn.z);
        pk.h[3] = __float2bfloat16(Dn.w);
        *(uint2*)(bm + (size_t)(R0 + lr)*64 + wv*16 + g*4) = pk.u;
        if (wv == 0 && lane < 16)
            ((float*)(wso + WS_LB))[R0 + lane] = lacc;
    }
}

// ---------------------------------------------------------------------------
// Epilogue: logprob[b] = laccF + laccB + log(alpha_mid . beta_mid); mean.
// ---------------------------------------------------------------------------
__global__ __launch_bounds__(256) void hmm_epi(
    const unsigned char* __restrict__ ws, float* __restrict__ out)
{
    __shared__ float red[4];
    const int tid = threadIdx.x;
    const int row = blockIdx.x * 256 + tid;
    const __hip_bfloat16* am = (const __hip_bfloat16*)(ws + WS_AM) + (size_t)row * 64;
    const __hip_bfloat16* bm = (const __hip_bfloat16*)(ws + WS_BM) + (size_t)row * 64;
    float dot = 0.f;
    #pragma unroll
    for (int k = 0; k < 8; k++) {
        union { bf16x8 v; __hip_bfloat16 h[8]; } ua, ub;
        ua.v = *(const bf16x8*)(am + k*8);
        ub.v = *(const bf16x8*)(bm + k*8);
        #pragma unroll
        for (int e = 0; e < 8; e++)
            dot += __bfloat162float(ua.h[e]) * __bfloat162float(ub.h[e]);
    }
    const float* lF = (const float*)(ws + WS_LF);
    const float* lB = (const float*)(ws + WS_LB);
    float lp = lF[row] + lB[row] + __logf(dot);
    #pragma unroll
    for (int d = 1; d < 64; d <<= 1) lp += __shfl_xor(lp, d);
    if ((tid & 63) == 0) red[tid >> 6] = lp;
    __syncthreads();
    if (tid == 0)
        atomicAdd(out, (red[0]+red[1]+red[2]+red[3]) * (1.0f / BATCH));
}

// ---------------------------------------------------------------------------
extern "C" void kernel_launch(void* const* d_in, const int* in_sizes, int n_in,
                              void* d_out, int out_size, void* d_ws, size_t ws_size,
                              hipStream_t stream) {
    const int*   y  = (const int*)  d_in[0];
    const float* T  = (const float*)d_in[1];
    const float* E  = (const float*)d_in[2];
    const float* Pi = (const float*)d_in[3];
    float* out = (float*)d_out;
    unsigned char* ws = (unsigned char*)d_ws;
    (void)ws_size;

    hipLaunchKernelGGL(hmm_pre,  dim3(1),         dim3(256), 0, stream, T, E, Pi, ws, out);
    hipLaunchKernelGGL(hmm_main, dim3(2*BATCH/16),dim3(256), 0, stream, y, ws, ws);
    hipLaunchKernelGGL(hmm_epi,  dim3(BATCH/256), dim3(256), 0, stream, ws, out);
}